// Round 4
// baseline (253.708 us; speedup 1.0000x reference)
//
#include <hip/hip_runtime.h>

// Problem: N=8192, K=10, M=3. ALL FLOAT32 (settled R0-R3: R1's inf = bf16-packed
// writes read back as fp32 words; R2/R3's exact-max|ref| error = unwritten
// second half of the 256 MB fp32 output buffer).
//   o[n][m]    = max_k(|x[n,k]| + |w1[m,k]|)     (8192 x 3, all >= 0)
//   dist[i][j] = max_m(o[i][m] + o[j][m])        (8192 x 8192 fp32, 256 MB)
// Fused single kernel, no d_ws. Store-BW bound: 256 MB / ~6.3 TB/s ≈ 41 us.

#define N_ROWS 8192
#define K_DIM 10
#define M_DIM 3

// Tile per 256-thread block: BI rows x BJ cols; each thread: 4 consecutive
// cols (one float4 store/row) x BI rows.
#define BJ 1024
#define BI 16

__global__ void __launch_bounds__(256) fused_dist_kernel(
        const float* __restrict__ x,   // 8192 x 10 fp32
        const float* __restrict__ w,   // 3 x 10 fp32
        float4* __restrict__ dist) {   // 8192 rows x 2048 float4
    const int tid = threadIdx.x;
    const int j4 = blockIdx.x * (BJ / 4) + tid;  // float4 index within row
    const int i0 = blockIdx.y * BI;

    // |w| into registers (block-uniform scalar loads, L1-resident).
    float aw[M_DIM][K_DIM];
#pragma unroll
    for (int m = 0; m < M_DIM; ++m)
#pragma unroll
        for (int k = 0; k < K_DIM; ++k)
            aw[m][k] = fabsf(w[m * K_DIM + k]);

    // Row o-values: threads 0..BI-1 each compute one row into LDS.
    __shared__ float so[BI][M_DIM];
    if (tid < BI) {
        const int i = i0 + tid;
        float ax[K_DIM];
#pragma unroll
        for (int k = 0; k < K_DIM; ++k) ax[k] = fabsf(x[i * K_DIM + k]);
#pragma unroll
        for (int m = 0; m < M_DIM; ++m) {
            float best = -1e30f;
#pragma unroll
            for (int k = 0; k < K_DIM; ++k) best = fmaxf(best, ax[k] + aw[m][k]);
            so[tid][m] = best;
        }
    }

    // Column o-values for this thread's 4 consecutive cols (j = j4*4 + t):
    // 40 consecutive floats of x -> 10 coalesced float4 loads (L1/L2-hit).
    float4 xv[10];
    const float4* x4 = (const float4*)x;
#pragma unroll
    for (int q = 0; q < 10; ++q) xv[q] = x4[j4 * 10 + q];
    const float* xf = (const float*)xv;

    float ob[4][M_DIM];
#pragma unroll
    for (int t = 0; t < 4; ++t) {
#pragma unroll
        for (int m = 0; m < M_DIM; ++m) {
            float best = -1e30f;
#pragma unroll
            for (int k = 0; k < K_DIM; ++k)
                best = fmaxf(best, fabsf(xf[t * K_DIM + k]) + aw[m][k]);
            ob[t][m] = best;
        }
    }

    __syncthreads();

    // Main store loop: BI rows x 4 cols per thread, 16B coalesced fp32 stores.
#pragma unroll
    for (int r = 0; r < BI; ++r) {
        const float a0 = so[r][0], a1 = so[r][1], a2 = so[r][2];  // LDS broadcast
        float4 v;
        v.x = fmaxf(fmaxf(a0 + ob[0][0], a1 + ob[0][1]), a2 + ob[0][2]);
        v.y = fmaxf(fmaxf(a0 + ob[1][0], a1 + ob[1][1]), a2 + ob[1][2]);
        v.z = fmaxf(fmaxf(a0 + ob[2][0], a1 + ob[2][1]), a2 + ob[2][2]);
        v.w = fmaxf(fmaxf(a0 + ob[3][0], a1 + ob[3][1]), a2 + ob[3][2]);
        dist[(size_t)(i0 + r) * (N_ROWS / 4) + j4] = v;
    }
}

extern "C" void kernel_launch(void* const* d_in, const int* in_sizes, int n_in,
                              void* d_out, int out_size, void* d_ws, size_t ws_size,
                              hipStream_t stream) {
    const float* x = (const float*)d_in[0];  // 8192*10 fp32
    const float* w = (const float*)d_in[1];  // 3*10 fp32
    (void)d_ws; (void)ws_size; (void)in_sizes; (void)n_in; (void)out_size;

    fused_dist_kernel<<<dim3(N_ROWS / BJ, N_ROWS / BI), dim3(256), 0, stream>>>(
        x, w, (float4*)d_out);
}